// Round 12
// baseline (366.531 us; speedup 1.0000x reference)
//
#include <hip/hip_runtime.h>
#include <math.h>

// Which XCD (chiplet) is this wave on? [HW-verified: learn_hip m09]
__device__ __forceinline__ int xcc_id() {
    int x;
    asm volatile("s_getreg_b32 %0, hwreg(HW_REG_XCC_ID)" : "=s"(x));
    return x & 7;
}

// Atomic f32 add. use_local=1 -> workgroup-scope (executes in the local XCD's
// L2; correct because each replica is only ever touched by blocks on that
// XCD). use_local=0 -> standard device scope (single buffer).
__device__ __forceinline__ void atom_add(float* p, float v, int use_local) {
    if (use_local)
        __hip_atomic_fetch_add(p, v, __ATOMIC_RELAXED, __HIP_MEMORY_SCOPE_WORKGROUP);
    else
        __hip_atomic_fetch_add(p, v, __ATOMIC_RELAXED, __HIP_MEMORY_SCOPE_AGENT);
}

// Stage 0: per-factor LSE table: flse[f][d][x] = logsumexp of factor f's
// 32-entry table over all axes except d, at state bit x.
__global__ void __launch_bounds__(256) k0_flse(
    const float* __restrict__ fbel,   // [F*32]
    float* __restrict__ flse,         // [F*10]
    int F)
{
    int f = blockIdx.x * 256 + threadIdx.x;
    if (f >= F) return;

    const float4* tab = reinterpret_cast<const float4*>(fbel + (size_t)f * 32);
    float v[32];
#pragma unroll
    for (int q = 0; q < 8; ++q) {
        float4 t = tab[q];
        v[q*4+0] = t.x; v[q*4+1] = t.y; v[q*4+2] = t.z; v[q*4+3] = t.w;
    }

    float m = v[0];
#pragma unroll
    for (int j = 1; j < 32; ++j) m = fmaxf(m, v[j]);

    float s[10];
#pragma unroll
    for (int i = 0; i < 10; ++i) s[i] = 0.f;
#pragma unroll
    for (int j = 0; j < 32; ++j) {
        float ex = __expf(v[j] - m);
#pragma unroll
        for (int d = 0; d < 5; ++d) s[d*2 + ((j >> (4 - d)) & 1)] += ex;
    }

    float* o = flse + (size_t)f * 10;
#pragma unroll
    for (int i = 0; i < 10; ++i) o[i] = m + __logf(s[i]);
}

// Stage 1: per-edge factor->var messages + scatter into per-XCD var replicas.
__global__ void __launch_bounds__(256) k1_f2v(
    const float* __restrict__ flse,   // [F*10]
    const float* __restrict__ pv2f,   // [E*2]
    const int*   __restrict__ fidx,
    const int*   __restrict__ vidx,
    const int*   __restrict__ evidx,
    float* __restrict__ f2v_out,      // [E*2]
    float* __restrict__ vacc_rep,     // [R][V*2] (pre-zeroed)
    long  vstride,                     // V*2 if replicated, ignored if !local
    int   use_local,
    int E)
{
    int e = blockIdx.x * 256 + threadIdx.x;
    if (e >= E) return;
    float* vacc = vacc_rep + (use_local ? (size_t)xcc_id() * vstride : 0);

    int f = fidx[e], d = evidx[e];
    float2 lse = *reinterpret_cast<const float2*>(flse + (size_t)f * 10 + d * 2);
    float2 p   = *reinterpret_cast<const float2*>(pv2f + 2 * (size_t)e);
    float p0 = (p.x == -INFINITY) ? 0.f : p.x;
    float p1 = (p.y == -INFINITY) ? 0.f : p.y;
    float r0 = lse.x - p0, r1 = lse.y - p1;

    *reinterpret_cast<float2*>(f2v_out + 2 * (size_t)e) = make_float2(r0, r1);

    int vi = vidx[e];
    atom_add(&vacc[2 * (size_t)vi],     r0, use_local);
    atom_add(&vacc[2 * (size_t)vi + 1], r1, use_local);
}

// Stage 2: sum replicas + log-softmax normalize -> var_out.
__global__ void __launch_bounds__(256) k2_varnorm(
    const float* __restrict__ vacc_rep,  // [R][V*2]
    float* __restrict__ var_out,         // [V*2]
    int V, int R, long vstride)
{
    int v = blockIdx.x * 256 + threadIdx.x;
    if (v >= V) return;
    float a0 = 0.f, a1 = 0.f;
    for (int r = 0; r < R; ++r) {
        float2 t = *reinterpret_cast<const float2*>(vacc_rep + (size_t)r * vstride + 2 * (size_t)v);
        a0 += t.x; a1 += t.y;
    }
    float m = fmaxf(a0, a1);
    float l = m + __logf(__expf(a0 - m) + __expf(a1 - m));
    var_out[2*v]   = a0 - l;
    var_out[2*v+1] = a1 - l;
}

// Stage 3: per-edge var->factor messages + scatter into per-XCD factor replicas.
__global__ void __launch_bounds__(256) k3_v2f(
    const float* __restrict__ vb,     // [V*2] normalized var beliefs
    const float* __restrict__ pf2v,   // [E*2]
    const int*   __restrict__ fidx,
    const int*   __restrict__ vidx,
    const int*   __restrict__ evidx,
    float* __restrict__ v2f_out,      // [E*2]
    float* __restrict__ facc_rep,     // [R][F*10] (pre-zeroed)
    long  fstride,                     // F*10
    int   use_local,
    int E)
{
    int e = blockIdx.x * 256 + threadIdx.x;
    if (e >= E) return;
    float* facc = facc_rep + (use_local ? (size_t)xcc_id() * fstride : 0);

    int vi = vidx[e];
    float2 b = *reinterpret_cast<const float2*>(vb + 2 * (size_t)vi);
    float2 p = *reinterpret_cast<const float2*>(pf2v + 2 * (size_t)e);
    float p0 = (p.x == -INFINITY) ? 0.f : p.x;
    float p1 = (p.y == -INFINITY) ? 0.f : p.y;
    float r0 = b.x - p0, r1 = b.y - p1;

    *reinterpret_cast<float2*>(v2f_out + 2 * (size_t)e) = make_float2(r0, r1);

    int f = fidx[e], d = evidx[e];
    atom_add(&facc[(size_t)f * 10 + d * 2],     r0, use_local);
    atom_add(&facc[(size_t)f * 10 + d * 2 + 1], r1, use_local);
}

// Stage 4: sum replicas, reconstruct 32-entry factor beliefs from 5 axis-
// pairs, add potentials, log-softmax over the 32 entries.
__global__ void __launch_bounds__(256) k4_fb(
    const float* __restrict__ facc_rep,  // [R][F*10]
    const float* __restrict__ pot,       // [F*32]
    float* __restrict__ fb_out,          // [F*32]
    int F, int R, long fstride)
{
    int f = blockIdx.x * 256 + threadIdx.x;
    if (f >= F) return;

    float a[10];
#pragma unroll
    for (int i = 0; i < 10; ++i) a[i] = 0.f;
    for (int r = 0; r < R; ++r) {
        const float* src = facc_rep + (size_t)r * fstride + (size_t)f * 10;
#pragma unroll
        for (int i = 0; i < 10; ++i) a[i] += src[i];
    }

    float t[32];
    const float4* pp = reinterpret_cast<const float4*>(pot + (size_t)f * 32);
#pragma unroll
    for (int q = 0; q < 8; ++q) {
        float4 x = pp[q];
        t[q*4+0] = x.x; t[q*4+1] = x.y; t[q*4+2] = x.z; t[q*4+3] = x.w;
    }

    float m = -INFINITY;
#pragma unroll
    for (int j = 0; j < 32; ++j) {
        float s = t[j];
#pragma unroll
        for (int d = 0; d < 5; ++d) s += a[d*2 + ((j >> (4 - d)) & 1)];
        t[j] = s;
        m = fmaxf(m, s);
    }
    float sum = 0.f;
#pragma unroll
    for (int j = 0; j < 32; ++j) sum += __expf(t[j] - m);
    float l = m + __logf(sum);

    float4* out = reinterpret_cast<float4*>(fb_out + (size_t)f * 32);
#pragma unroll
    for (int q = 0; q < 8; ++q) {
        float4 x;
        x.x = t[q*4+0] - l; x.y = t[q*4+1] - l;
        x.z = t[q*4+2] - l; x.w = t[q*4+3] - l;
        out[q] = x;
    }
}

extern "C" void kernel_launch(void* const* d_in, const int* in_sizes, int n_in,
                              void* d_out, int out_size, void* d_ws, size_t ws_size,
                              hipStream_t stream)
{
    const float* fbel  = (const float*)d_in[0];   // factor_beliefs [F,32]
    const float* pot   = (const float*)d_in[2];   // factor_potentials [F,32]
    const float* pv2f  = (const float*)d_in[3];   // prv v->f msgs [E,2]
    const float* pf2v  = (const float*)d_in[4];   // prv f->v msgs [E,2]
    const int*   fidx  = (const int*)d_in[5];
    const int*   vidx  = (const int*)d_in[6];
    const int*   evidx = (const int*)d_in[7];

    const int E  = in_sizes[5];
    const int F_ = in_sizes[0] / 32;
    const int V_ = in_sizes[1] / 2;

    float* out     = (float*)d_out;
    float* var_out = out;                          // [V*2]
    float* fb_out  = out + (size_t)V_ * 2;         // [F*32]
    float* f2v_out = fb_out + (size_t)F_ * 32;     // [E*2]
    float* v2f_out = f2v_out + (size_t)E * 2;      // [E*2]

    // flse[F*10] temporarily lives in the v2f_out region (E*2 == F*10 floats
    // here); it is fully consumed by k1 before k3 overwrites the region.
    float* flse = v2f_out;

    const long V2  = (long)V_ * 2;
    const long F10 = (long)F_ * 10;

    // Per-XCD replicated accumulators in workspace (fallback: 1 replica,
    // device-scope atomics).
    int R = (ws_size >= (size_t)8 * (size_t)(V2 + F10) * sizeof(float)) ? 8 : 1;
    int use_local = (R == 8) ? 1 : 0;
    float* vacc_rep = (float*)d_ws;                // [R][V*2]
    float* facc_rep = vacc_rep + (size_t)R * V2;   // [R][F*10]

    // Workspace is poisoned (0xAA) before every timed launch -> zero replicas.
    (void)hipMemsetAsync(d_ws, 0, (size_t)R * (size_t)(V2 + F10) * sizeof(float),
                         stream);

    k0_flse   <<<dim3((F_ + 255) / 256), dim3(256), 0, stream>>>(fbel, flse, F_);
    k1_f2v    <<<dim3((E  + 255) / 256), dim3(256), 0, stream>>>(
        flse, pv2f, fidx, vidx, evidx, f2v_out, vacc_rep, V2, use_local, E);
    k2_varnorm<<<dim3((V_ + 255) / 256), dim3(256), 0, stream>>>(
        vacc_rep, var_out, V_, R, V2);
    k3_v2f    <<<dim3((E  + 255) / 256), dim3(256), 0, stream>>>(
        var_out, pf2v, fidx, vidx, evidx, v2f_out, facc_rep, F10, use_local, E);
    k4_fb     <<<dim3((F_ + 255) / 256), dim3(256), 0, stream>>>(
        facc_rep, pot, fb_out, F_, R, F10);
}

// Round 16
// 348.283 us; speedup vs baseline: 1.0524x; 1.0524x over previous
//
#include <hip/hip_runtime.h>
#include <math.h>

// Which XCD (chiplet) is this wave on? [HW-verified: learn_hip m09]
__device__ __forceinline__ int xcc_id() {
    int x;
    asm volatile("s_getreg_b32 %0, hwreg(HW_REG_XCC_ID)" : "=s"(x));
    return x & 7;
}

// Weakest-scope atomic add (scope-placement experiment arm).
__device__ __forceinline__ void atom_add_l2(float* p, float v) {
    __hip_atomic_fetch_add(p, v, __ATOMIC_RELAXED, __HIP_MEMORY_SCOPE_WAVEFRONT);
}

// Device-scope (memory-side) atomic add — baseline semantics.
__device__ __forceinline__ void atom_add_dev(float* p, float v) {
    __hip_atomic_fetch_add(p, v, __ATOMIC_RELAXED, __HIP_MEMORY_SCOPE_AGENT);
}

// Stage 0: per-factor LSE table: flse[f][d][x] = logsumexp of factor f's
// 32-entry table over all axes except d, at state bit x.
__global__ void __launch_bounds__(256) k0_flse(
    const float* __restrict__ fbel,   // [F*32]
    float* __restrict__ flse,         // [F*10]
    int F)
{
    int f = blockIdx.x * 256 + threadIdx.x;
    if (f >= F) return;

    const float4* tab = reinterpret_cast<const float4*>(fbel + (size_t)f * 32);
    float v[32];
#pragma unroll
    for (int q = 0; q < 8; ++q) {
        float4 t = tab[q];
        v[q*4+0] = t.x; v[q*4+1] = t.y; v[q*4+2] = t.z; v[q*4+3] = t.w;
    }

    float m = v[0];
#pragma unroll
    for (int j = 1; j < 32; ++j) m = fmaxf(m, v[j]);

    float s[10];
#pragma unroll
    for (int i = 0; i < 10; ++i) s[i] = 0.f;
#pragma unroll
    for (int j = 0; j < 32; ++j) {
        float ex = __expf(v[j] - m);
#pragma unroll
        for (int d = 0; d < 5; ++d) s[d*2 + ((j >> (4 - d)) & 1)] += ex;
    }

    float* o = flse + (size_t)f * 10;
#pragma unroll
    for (int i = 0; i < 10; ++i) o[i] = m + __logf(s[i]);
}

// Stage 1 (SCOPE ARM): per-edge factor->var messages + wavefront-scope
// scatter into per-XCD var replicas. Control: rounds 4/12 measured this
// kernel with device scope at 108 us / WRITE 70258 KB.
__global__ void __launch_bounds__(256) k1_f2v(
    const float* __restrict__ flse,   // [F*10]
    const float* __restrict__ pv2f,   // [E*2]
    const int*   __restrict__ fidx,
    const int*   __restrict__ vidx,
    const int*   __restrict__ evidx,
    float* __restrict__ f2v_out,      // [E*2]
    float* __restrict__ vacc_rep,     // [8][V*2] (pre-zeroed)
    long  vstride,                    // V*2
    int E)
{
    int e = blockIdx.x * 256 + threadIdx.x;
    if (e >= E) return;
    float* vacc = vacc_rep + (size_t)xcc_id() * vstride;

    int f = fidx[e], d = evidx[e];
    float2 lse = *reinterpret_cast<const float2*>(flse + (size_t)f * 10 + d * 2);
    float2 p   = *reinterpret_cast<const float2*>(pv2f + 2 * (size_t)e);
    float p0 = (p.x == -INFINITY) ? 0.f : p.x;
    float p1 = (p.y == -INFINITY) ? 0.f : p.y;
    float r0 = lse.x - p0, r1 = lse.y - p1;

    *reinterpret_cast<float2*>(f2v_out + 2 * (size_t)e) = make_float2(r0, r1);

    int vi = vidx[e];
    atom_add_l2(&vacc[2 * (size_t)vi],     r0);
    atom_add_l2(&vacc[2 * (size_t)vi + 1], r1);
}

// Stage 2: sum the 8 replicas + log-softmax normalize -> var_out.
__global__ void __launch_bounds__(256) k2_varnorm(
    const float* __restrict__ vacc_rep,  // [8][V*2]
    float* __restrict__ var_out,         // [V*2]
    int V, long vstride)
{
    int v = blockIdx.x * 256 + threadIdx.x;
    if (v >= V) return;
    float a0 = 0.f, a1 = 0.f;
#pragma unroll
    for (int r = 0; r < 8; ++r) {
        float2 t = *reinterpret_cast<const float2*>(
            vacc_rep + (size_t)r * vstride + 2 * (size_t)v);
        a0 += t.x; a1 += t.y;
    }
    float m = fmaxf(a0, a1);
    float l = m + __logf(__expf(a0 - m) + __expf(a1 - m));
    var_out[2*v]   = a0 - l;
    var_out[2*v+1] = a1 - l;
}

// Stage 3 (ILP ARM): 4 edges per thread, coalesced stride-256 within the
// block; device-scope atomics into single facc (baseline semantics).
// Control: same-structure 1-edge/thread kernel ran ~104-110 us.
__global__ void __launch_bounds__(256) k3_v2f(
    const float* __restrict__ vb,     // [V*2] normalized var beliefs
    const float* __restrict__ pf2v,   // [E*2]
    const int*   __restrict__ fidx,
    const int*   __restrict__ vidx,
    const int*   __restrict__ evidx,
    float* __restrict__ v2f_out,      // [E*2]
    float* __restrict__ facc,         // [F*10] (pre-zeroed) layout [f][d][x]
    int E)
{
    int base = blockIdx.x * 1024 + threadIdx.x;
#pragma unroll
    for (int i = 0; i < 4; ++i) {
        int e = base + i * 256;
        if (e >= E) continue;

        int vi = vidx[e];
        float2 b = *reinterpret_cast<const float2*>(vb + 2 * (size_t)vi);
        float2 p = *reinterpret_cast<const float2*>(pf2v + 2 * (size_t)e);
        float p0 = (p.x == -INFINITY) ? 0.f : p.x;
        float p1 = (p.y == -INFINITY) ? 0.f : p.y;
        float r0 = b.x - p0, r1 = b.y - p1;

        *reinterpret_cast<float2*>(v2f_out + 2 * (size_t)e) = make_float2(r0, r1);

        int f = fidx[e], d = evidx[e];
        atom_add_dev(&facc[(size_t)f * 10 + d * 2],     r0);
        atom_add_dev(&facc[(size_t)f * 10 + d * 2 + 1], r1);
    }
}

// Stage 4: reconstruct 32-entry factor beliefs from 5 axis-pairs, add
// potentials, log-softmax over the 32 entries.
__global__ void __launch_bounds__(256) k4_fb(
    const float* __restrict__ facc,   // [F*10]
    const float* __restrict__ pot,    // [F*32]
    float* __restrict__ fb_out,       // [F*32]
    int F)
{
    int f = blockIdx.x * 256 + threadIdx.x;
    if (f >= F) return;

    float a[10];
#pragma unroll
    for (int i = 0; i < 10; ++i) a[i] = facc[(size_t)f * 10 + i];

    float t[32];
    const float4* pp = reinterpret_cast<const float4*>(pot + (size_t)f * 32);
#pragma unroll
    for (int q = 0; q < 8; ++q) {
        float4 x = pp[q];
        t[q*4+0] = x.x; t[q*4+1] = x.y; t[q*4+2] = x.z; t[q*4+3] = x.w;
    }

    float m = -INFINITY;
#pragma unroll
    for (int j = 0; j < 32; ++j) {
        float s = t[j];
#pragma unroll
        for (int d = 0; d < 5; ++d) s += a[d*2 + ((j >> (4 - d)) & 1)];
        t[j] = s;
        m = fmaxf(m, s);
    }
    float sum = 0.f;
#pragma unroll
    for (int j = 0; j < 32; ++j) sum += __expf(t[j] - m);
    float l = m + __logf(sum);

    float4* out = reinterpret_cast<float4*>(fb_out + (size_t)f * 32);
#pragma unroll
    for (int q = 0; q < 8; ++q) {
        float4 x;
        x.x = t[q*4+0] - l; x.y = t[q*4+1] - l;
        x.z = t[q*4+2] - l; x.w = t[q*4+3] - l;
        out[q] = x;
    }
}

extern "C" void kernel_launch(void* const* d_in, const int* in_sizes, int n_in,
                              void* d_out, int out_size, void* d_ws, size_t ws_size,
                              hipStream_t stream)
{
    const float* fbel  = (const float*)d_in[0];   // factor_beliefs [F,32]
    const float* pot   = (const float*)d_in[2];   // factor_potentials [F,32]
    const float* pv2f  = (const float*)d_in[3];   // prv v->f msgs [E,2]
    const float* pf2v  = (const float*)d_in[4];   // prv f->v msgs [E,2]
    const int*   fidx  = (const int*)d_in[5];
    const int*   vidx  = (const int*)d_in[6];
    const int*   evidx = (const int*)d_in[7];

    const int E  = in_sizes[5];
    const int F_ = in_sizes[0] / 32;
    const int V_ = in_sizes[1] / 2;

    float* out     = (float*)d_out;
    float* var_out = out;                          // [V*2]
    float* fb_out  = out + (size_t)V_ * 2;         // [F*32]
    float* f2v_out = fb_out + (size_t)F_ * 32;     // [E*2]
    float* v2f_out = f2v_out + (size_t)E * 2;      // [E*2]

    // flse[F*10] temporarily lives in the v2f_out region (E*2 == F*10 floats
    // here); it is fully consumed by k1 before k3 overwrites the region.
    float* flse = v2f_out;

    const long V2  = (long)V_ * 2;
    const long F10 = (long)F_ * 10;

    // vacc replicas [8][V*2] live in the fb_out region (written only by k4,
    // long after k2 consumed the replicas). facc lives in workspace (8 MB).
    float* vacc_rep = fb_out;                      // [8][V*2] = 6.4 MB
    float* facc     = (float*)d_ws;                // [F*10]   = 8 MB

    // Zero the accumulators (workspace/outputs are poisoned 0xAA).
    (void)hipMemsetAsync(vacc_rep, 0, (size_t)8 * V2 * sizeof(float), stream);
    (void)hipMemsetAsync(facc,     0, (size_t)F10 * sizeof(float), stream);

    k0_flse   <<<dim3((F_ + 255) / 256), dim3(256), 0, stream>>>(fbel, flse, F_);
    k1_f2v    <<<dim3((E  + 255) / 256), dim3(256), 0, stream>>>(
        flse, pv2f, fidx, vidx, evidx, f2v_out, vacc_rep, V2, E);
    k2_varnorm<<<dim3((V_ + 255) / 256), dim3(256), 0, stream>>>(
        vacc_rep, var_out, V_, V2);
    k3_v2f    <<<dim3((E  + 1023) / 1024), dim3(256), 0, stream>>>(
        var_out, pf2v, fidx, vidx, evidx, v2f_out, facc, E);
    k4_fb     <<<dim3((F_ + 255) / 256), dim3(256), 0, stream>>>(
        facc, pot, fb_out, F_);
}